// Round 3
// baseline (225.975 us; speedup 1.0000x reference)
//
#include <hip/hip_runtime.h>
#include <hip/hip_bf16.h>

#define DM 1024
#define DH 64
#define TT 2048

typedef __attribute__((ext_vector_type(8))) short bf16x8;
typedef __attribute__((ext_vector_type(4))) short s16x4;
typedef __attribute__((ext_vector_type(4))) float f32x4;

static __device__ __forceinline__ short f2bf(float f) {
  union { __hip_bfloat16 h; short s; } u;
  u.h = __float2bfloat16(f);
  return u.s;
}

// ---------------- kernel 1: W -> W^T bf16, layout [3][64 n][1024 k] ----------------
__global__ __launch_bounds__(256) void convw_kernel(const float* __restrict__ Wq,
                                                    const float* __restrict__ Wk,
                                                    const float* __restrict__ Wv,
                                                    short* __restrict__ Wt) {
  int idx = blockIdx.x * 256 + threadIdx.x;
  if (idx >= 3 * 64 * 1024) return;
  int wsel = idx >> 16;
  int rem  = idx & 65535;
  int n = rem >> 10;
  int k = rem & 1023;
  const float* W = (wsel == 0) ? Wq : (wsel == 1) ? Wk : Wv;
  Wt[idx] = f2bf(W[k * DH + n]);
}

// ---------------- kernel 2: projection. 1 wave = 16 rows x 192 cols (q|k|v) --------
// Qb,Kb: [B*T][64] bf16 row-major. Vt: [B][64 dim][2048 t] bf16 (transposed).
__global__ __launch_bounds__(64) void proj_kernel(const float* __restrict__ x,
                                                  const short* __restrict__ Wt,
                                                  short* __restrict__ Qb,
                                                  short* __restrict__ Kb,
                                                  short* __restrict__ Vt) {
  int lane = threadIdx.x & 63;
  int l15 = lane & 15, lq = lane >> 4;
  int row0 = blockIdx.x * 16;  // 1024 blocks cover 16384 rows
  f32x4 acc[12];
  #pragma unroll
  for (int t = 0; t < 12; ++t) acc[t] = (f32x4){0.f, 0.f, 0.f, 0.f};

  const float* xp = x + (size_t)(row0 + l15) * DM + 8 * lq;
  #pragma unroll 2
  for (int ks = 0; ks < 32; ++ks) {
    const float4* ap = reinterpret_cast<const float4*>(xp + ks * 32);
    float4 a0 = ap[0], a1 = ap[1];
    bf16x8 af;
    af[0] = f2bf(a0.x); af[1] = f2bf(a0.y); af[2] = f2bf(a0.z); af[3] = f2bf(a0.w);
    af[4] = f2bf(a1.x); af[5] = f2bf(a1.y); af[6] = f2bf(a1.z); af[7] = f2bf(a1.w);
    const short* wp = Wt + (size_t)l15 * DM + ks * 32 + 8 * lq;
    #pragma unroll
    for (int t = 0; t < 12; ++t) {
      bf16x8 bfr = *reinterpret_cast<const bf16x8*>(wp + (size_t)t * 16 * DM);
      acc[t] = __builtin_amdgcn_mfma_f32_16x16x32_bf16(af, bfr, acc[t], 0, 0, 0);
    }
  }

  // epilogue: D layout col=lane&15, row=(lane>>4)*4+r
  #pragma unroll
  for (int nt = 0; nt < 4; ++nt)
    #pragma unroll
    for (int r = 0; r < 4; ++r) {
      int row = row0 + lq * 4 + r;
      Qb[(size_t)row * DH + nt * 16 + l15] = f2bf(acc[nt][r]);
      Kb[(size_t)row * DH + nt * 16 + l15] = f2bf(acc[4 + nt][r]);
    }
  int b = row0 >> 11;            // row0 / 2048 (blocks never straddle batches)
  int tloc = (row0 & 2047) + lq * 4;
  #pragma unroll
  for (int nt = 0; nt < 4; ++nt) {
    int dim = nt * 16 + l15;
    s16x4 pk;
    #pragma unroll
    for (int r = 0; r < 4; ++r) pk[r] = f2bf(acc[8 + nt][r]);
    *reinterpret_cast<s16x4*>(Vt + ((size_t)b * DH + dim) * TT + tloc) = pk;
  }
}

// ---------------- kernel 3: causal flash attention, 1 wave per 16-row Q tile -------
__global__ __launch_bounds__(64) void flash_kernel(const short* __restrict__ Qb,
                                                   const short* __restrict__ Kb,
                                                   const short* __restrict__ Vt,
                                                   float* __restrict__ out) {
  __shared__ short Pl[16][72];   // pad to 72 shorts: 16B-aligned rows, 2-way bank alias (free)
  int lane = threadIdx.x & 63;
  int l15 = lane & 15, lq = lane >> 4;
  int qt = 127 - (blockIdx.x >> 3);   // descending work order for load balance
  int b  = blockIdx.x & 7;
  int row0 = qt * 16;

  const short* qp = Qb + ((size_t)(b * TT + row0 + l15)) * DH + 8 * lq;
  bf16x8 qf0 = *reinterpret_cast<const bf16x8*>(qp);
  bf16x8 qf1 = *reinterpret_cast<const bf16x8*>(qp + 32);

  float mrow[4] = {-1e30f, -1e30f, -1e30f, -1e30f};
  float lrow[4] = {0.f, 0.f, 0.f, 0.f};
  f32x4 o[4];
  #pragma unroll
  for (int nt = 0; nt < 4; ++nt) o[nt] = (f32x4){0.f, 0.f, 0.f, 0.f};

  int nkt = (qt >> 2) + 1;       // causal: key tiles 0..(row0+15)/64
  for (int kt = 0; kt < nkt; ++kt) {
    int k0 = kt * 64;
    // ---- S = (Q K^T) ----
    f32x4 s[4];
    #pragma unroll
    for (int nt = 0; nt < 4; ++nt) s[nt] = (f32x4){0.f, 0.f, 0.f, 0.f};
    #pragma unroll
    for (int nt = 0; nt < 4; ++nt) {
      const short* kp = Kb + ((size_t)(b * TT + k0 + nt * 16 + l15)) * DH + 8 * lq;
      bf16x8 b0 = *reinterpret_cast<const bf16x8*>(kp);
      bf16x8 b1 = *reinterpret_cast<const bf16x8*>(kp + 32);
      s[nt] = __builtin_amdgcn_mfma_f32_16x16x32_bf16(qf0, b0, s[nt], 0, 0, 0);
      s[nt] = __builtin_amdgcn_mfma_f32_16x16x32_bf16(qf1, b1, s[nt], 0, 0, 0);
    }
    // ---- scale + causal mask + row max ----
    float rmax[4] = {-1e30f, -1e30f, -1e30f, -1e30f};
    #pragma unroll
    for (int nt = 0; nt < 4; ++nt) {
      int key = k0 + nt * 16 + l15;
      #pragma unroll
      for (int r = 0; r < 4; ++r) {
        int qr = row0 + lq * 4 + r;
        float v = s[nt][r] * 0.03125f;   // 1/sqrt(1024)
        v = (key <= qr) ? v : -1e30f;
        s[nt][r] = v;
        rmax[r] = fmaxf(rmax[r], v);
      }
    }
    #pragma unroll
    for (int r = 0; r < 4; ++r)
      #pragma unroll
      for (int d = 1; d < 16; d <<= 1)
        rmax[r] = fmaxf(rmax[r], __shfl_xor(rmax[r], d));
    // ---- online softmax update ----
    float alpha[4], rs[4];
    #pragma unroll
    for (int r = 0; r < 4; ++r) {
      float mn = fmaxf(mrow[r], rmax[r]);
      alpha[r] = __expf(mrow[r] - mn);
      mrow[r] = mn;
      rs[r] = 0.f;
    }
    #pragma unroll
    for (int nt = 0; nt < 4; ++nt)
      #pragma unroll
      for (int r = 0; r < 4; ++r) {
        float p = __expf(s[nt][r] - mrow[r]);
        s[nt][r] = p;
        rs[r] += p;
      }
    #pragma unroll
    for (int r = 0; r < 4; ++r) {
      #pragma unroll
      for (int d = 1; d < 16; d <<= 1)
        rs[r] += __shfl_xor(rs[r], d);
      lrow[r] = lrow[r] * alpha[r] + rs[r];
    }
    #pragma unroll
    for (int nt = 0; nt < 4; ++nt) {
      o[nt][0] *= alpha[0]; o[nt][1] *= alpha[1];
      o[nt][2] *= alpha[2]; o[nt][3] *= alpha[3];
    }
    // ---- P (D-layout) -> LDS transpose -> A-operand layout ----
    #pragma unroll
    for (int nt = 0; nt < 4; ++nt)
      #pragma unroll
      for (int r = 0; r < 4; ++r)
        Pl[lq * 4 + r][nt * 16 + l15] = f2bf(s[nt][r]);
    // same-wave DS ops are in-order; no cross-wave sharing -> no barrier needed
    bf16x8 pa0 = *reinterpret_cast<const bf16x8*>(&Pl[l15][8 * lq]);
    bf16x8 pa1 = *reinterpret_cast<const bf16x8*>(&Pl[l15][32 + 8 * lq]);
    // ---- O += P V  (V^T gives contiguous B-fragments) ----
    #pragma unroll
    for (int nt = 0; nt < 4; ++nt) {
      const short* vp = Vt + ((size_t)(b * DH + nt * 16 + l15)) * TT + k0 + 8 * lq;
      bf16x8 v0 = *reinterpret_cast<const bf16x8*>(vp);
      bf16x8 v1 = *reinterpret_cast<const bf16x8*>(vp + 32);
      o[nt] = __builtin_amdgcn_mfma_f32_16x16x32_bf16(pa0, v0, o[nt], 0, 0, 0);
      o[nt] = __builtin_amdgcn_mfma_f32_16x16x32_bf16(pa1, v1, o[nt], 0, 0, 0);
    }
  }
  // ---- epilogue ----
  #pragma unroll
  for (int nt = 0; nt < 4; ++nt)
    #pragma unroll
    for (int r = 0; r < 4; ++r) {
      size_t oidx = ((size_t)(b * TT + row0 + lq * 4 + r)) * DH + nt * 16 + l15;
      out[oidx] = o[nt][r] / lrow[r];
    }
}

extern "C" void kernel_launch(void* const* d_in, const int* in_sizes, int n_in,
                              void* d_out, int out_size, void* d_ws, size_t ws_size,
                              hipStream_t stream) {
  const float* x  = (const float*)d_in[0];
  const float* Wq = (const float*)d_in[1];
  const float* Wk = (const float*)d_in[2];
  const float* Wv = (const float*)d_in[3];
  float* out = (float*)d_out;
  char* ws = (char*)d_ws;
  // workspace layout (bf16): Qb 2MB | Kb 2MB | Vt 2MB | Wt 0.4MB
  short* Qb = (short*)(ws);
  short* Kb = (short*)(ws + (2ull << 20));
  short* Vt = (short*)(ws + (4ull << 20));
  short* Wt = (short*)(ws + (6ull << 20));

  convw_kernel<<<dim3(768), dim3(256), 0, stream>>>(Wq, Wk, Wv, Wt);
  proj_kernel<<<dim3(1024), dim3(64), 0, stream>>>(x, Wt, Qb, Kb, Vt);
  flash_kernel<<<dim3(1024), dim3(64), 0, stream>>>(Qb, Kb, Vt, out);
}

// Round 5
// 192.725 us; speedup vs baseline: 1.1725x; 1.1725x over previous
//
#include <hip/hip_runtime.h>
#include <hip/hip_bf16.h>

#define DM 1024
#define DH 64
#define TT 2048

typedef __attribute__((ext_vector_type(8))) short bf16x8;
typedef __attribute__((ext_vector_type(4))) short s16x4;
typedef __attribute__((ext_vector_type(4))) float f32x4;

static __device__ __forceinline__ short f2bf(float f) {
  union { __hip_bfloat16 h; short s; } u;
  u.h = __float2bfloat16(f);
  return u.s;
}

// ---------------- kernel 1: W -> W^T bf16, layout [3][64 n][1024 k] ----------------
__global__ __launch_bounds__(256) void convw_kernel(const float* __restrict__ Wq,
                                                    const float* __restrict__ Wk,
                                                    const float* __restrict__ Wv,
                                                    short* __restrict__ Wt) {
  int idx = blockIdx.x * 256 + threadIdx.x;
  if (idx >= 3 * 64 * 1024) return;
  int wsel = idx >> 16;
  int rem  = idx & 65535;
  int n = rem >> 10;
  int k = rem & 1023;
  const float* W = (wsel == 0) ? Wq : (wsel == 1) ? Wk : Wv;
  Wt[idx] = f2bf(W[k * DH + n]);
}

// ---------------- kernel 2: projection. 3 waves/block, wave w computes one of Q/K/V
// for 16 rows x 64 cols. 1024 blocks x 192 thr = 3072 waves (3/SIMD).
// Qb,Kb: [B*T][64] bf16 row-major. Vt: [B][64 dim][2048 t] bf16 (transposed).
__global__ __launch_bounds__(192) void proj_kernel(const float* __restrict__ x,
                                                   const short* __restrict__ Wt,
                                                   short* __restrict__ Qb,
                                                   short* __restrict__ Kb,
                                                   short* __restrict__ Vt) {
  int w    = threadIdx.x >> 6;   // 0=Q 1=K 2=V
  int lane = threadIdx.x & 63;
  int l15 = lane & 15, lq = lane >> 4;
  int row0 = blockIdx.x * 16;
  f32x4 acc[4];
  #pragma unroll
  for (int t = 0; t < 4; ++t) acc[t] = (f32x4){0.f, 0.f, 0.f, 0.f};

  const float* xp = x + (size_t)(row0 + l15) * DM + 8 * lq;
  const short* wbase = Wt + w * (DH * DM);   // this wave's weight matrix (n-major)
  #pragma unroll 2
  for (int ks = 0; ks < 32; ++ks) {
    const float4* ap = reinterpret_cast<const float4*>(xp + ks * 32);
    float4 a0 = ap[0], a1 = ap[1];
    bf16x8 af;
    af[0] = f2bf(a0.x); af[1] = f2bf(a0.y); af[2] = f2bf(a0.z); af[3] = f2bf(a0.w);
    af[4] = f2bf(a1.x); af[5] = f2bf(a1.y); af[6] = f2bf(a1.z); af[7] = f2bf(a1.w);
    const short* wp = wbase + (size_t)l15 * DM + ks * 32 + 8 * lq;
    #pragma unroll
    for (int nt = 0; nt < 4; ++nt) {
      bf16x8 bfr = *reinterpret_cast<const bf16x8*>(wp + (size_t)nt * 16 * DM);
      acc[nt] = __builtin_amdgcn_mfma_f32_16x16x32_bf16(af, bfr, acc[nt], 0, 0, 0);
    }
  }

  // epilogue: D layout col=lane&15, row=(lane>>4)*4+r
  if (w < 2) {
    short* dst = (w == 0) ? Qb : Kb;
    #pragma unroll
    for (int nt = 0; nt < 4; ++nt)
      #pragma unroll
      for (int r = 0; r < 4; ++r) {
        int row = row0 + lq * 4 + r;
        dst[(size_t)row * DH + nt * 16 + l15] = f2bf(acc[nt][r]);
      }
  } else {
    int b = row0 >> 11;            // blocks never straddle batches
    int tloc = (row0 & 2047) + lq * 4;
    #pragma unroll
    for (int nt = 0; nt < 4; ++nt) {
      int dim = nt * 16 + l15;
      s16x4 pk;
      #pragma unroll
      for (int r = 0; r < 4; ++r) pk[r] = f2bf(acc[nt][r]);
      *reinterpret_cast<s16x4*>(Vt + ((size_t)b * DH + dim) * TT + tloc) = pk;
    }
  }
}

// ---------------- kernel 3: causal flash attention ----------------
// 4 waves/block on one 16-row Q tile; wave w handles key tiles kt = w, w+4, ...
// each with private online-softmax state; LDS merge at the end.
// 1024 blocks x 256 thr = 4096 waves (4/SIMD).
__global__ __launch_bounds__(256) void flash_kernel(const short* __restrict__ Qb,
                                                    const short* __restrict__ Kb,
                                                    const short* __restrict__ Vt,
                                                    float* __restrict__ out) {
  __shared__ short Pl[4][16][72];   // per-wave P transpose buffer (rows 144B = 16B-aligned)
  __shared__ float Om[4][16][64];   // per-wave partial O
  __shared__ float Mm[4][16];
  __shared__ float Lm[4][16];
  int w    = threadIdx.x >> 6;
  int lane = threadIdx.x & 63;
  int l15 = lane & 15, lq = lane >> 4;
  int qt = 127 - (blockIdx.x >> 3);   // descending work order for load balance
  int b  = blockIdx.x & 7;
  int row0 = qt * 16;

  const short* qp = Qb + ((size_t)(b * TT + row0 + l15)) * DH + 8 * lq;
  bf16x8 qf0 = *reinterpret_cast<const bf16x8*>(qp);
  bf16x8 qf1 = *reinterpret_cast<const bf16x8*>(qp + 32);

  float mrow[4] = {-1e30f, -1e30f, -1e30f, -1e30f};
  float lrow[4] = {0.f, 0.f, 0.f, 0.f};
  f32x4 o[4];
  #pragma unroll
  for (int nt = 0; nt < 4; ++nt) o[nt] = (f32x4){0.f, 0.f, 0.f, 0.f};

  int nkt = (qt >> 2) + 1;       // causal: key tiles 0..(row0+15)/64
  for (int kt = w; kt < nkt; kt += 4) {
    int k0 = kt * 64;
    // ---- S = Q K^T ----
    f32x4 s[4];
    #pragma unroll
    for (int nt = 0; nt < 4; ++nt) s[nt] = (f32x4){0.f, 0.f, 0.f, 0.f};
    #pragma unroll
    for (int nt = 0; nt < 4; ++nt) {
      const short* kp = Kb + ((size_t)(b * TT + k0 + nt * 16 + l15)) * DH + 8 * lq;
      bf16x8 b0 = *reinterpret_cast<const bf16x8*>(kp);
      bf16x8 b1 = *reinterpret_cast<const bf16x8*>(kp + 32);
      s[nt] = __builtin_amdgcn_mfma_f32_16x16x32_bf16(qf0, b0, s[nt], 0, 0, 0);
      s[nt] = __builtin_amdgcn_mfma_f32_16x16x32_bf16(qf1, b1, s[nt], 0, 0, 0);
    }
    // ---- scale + causal mask + row max ----
    float rmax[4] = {-1e30f, -1e30f, -1e30f, -1e30f};
    #pragma unroll
    for (int nt = 0; nt < 4; ++nt) {
      int key = k0 + nt * 16 + l15;
      #pragma unroll
      for (int r = 0; r < 4; ++r) {
        int qr = row0 + lq * 4 + r;
        float v = s[nt][r] * 0.03125f;   // 1/sqrt(1024)
        v = (key <= qr) ? v : -1e30f;
        s[nt][r] = v;
        rmax[r] = fmaxf(rmax[r], v);
      }
    }
    #pragma unroll
    for (int r = 0; r < 4; ++r)
      #pragma unroll
      for (int d = 1; d < 16; d <<= 1)
        rmax[r] = fmaxf(rmax[r], __shfl_xor(rmax[r], d));
    // ---- online softmax update (per-wave private state) ----
    float alpha[4], rs[4];
    #pragma unroll
    for (int r = 0; r < 4; ++r) {
      float mn = fmaxf(mrow[r], rmax[r]);
      alpha[r] = __expf(mrow[r] - mn);
      mrow[r] = mn;
      rs[r] = 0.f;
    }
    #pragma unroll
    for (int nt = 0; nt < 4; ++nt)
      #pragma unroll
      for (int r = 0; r < 4; ++r) {
        float p = __expf(s[nt][r] - mrow[r]);
        s[nt][r] = p;
        rs[r] += p;
      }
    #pragma unroll
    for (int r = 0; r < 4; ++r) {
      #pragma unroll
      for (int d = 1; d < 16; d <<= 1)
        rs[r] += __shfl_xor(rs[r], d);
      lrow[r] = lrow[r] * alpha[r] + rs[r];
    }
    #pragma unroll
    for (int nt = 0; nt < 4; ++nt) {
      o[nt][0] *= alpha[0]; o[nt][1] *= alpha[1];
      o[nt][2] *= alpha[2]; o[nt][3] *= alpha[3];
    }
    // ---- P (D-layout) -> LDS transpose -> A-operand layout (wave-private) ----
    #pragma unroll
    for (int nt = 0; nt < 4; ++nt)
      #pragma unroll
      for (int r = 0; r < 4; ++r)
        Pl[w][lq * 4 + r][nt * 16 + l15] = f2bf(s[nt][r]);
    // same-wave DS ops in-order; buffer is wave-private -> no barrier
    bf16x8 pa0 = *reinterpret_cast<const bf16x8*>(&Pl[w][l15][8 * lq]);
    bf16x8 pa1 = *reinterpret_cast<const bf16x8*>(&Pl[w][l15][32 + 8 * lq]);
    // ---- O += P V ----
    #pragma unroll
    for (int nt = 0; nt < 4; ++nt) {
      const short* vp = Vt + ((size_t)(b * DH + nt * 16 + l15)) * TT + k0 + 8 * lq;
      bf16x8 v0 = *reinterpret_cast<const bf16x8*>(vp);
      bf16x8 v1 = *reinterpret_cast<const bf16x8*>(vp + 32);
      o[nt] = __builtin_amdgcn_mfma_f32_16x16x32_bf16(pa0, v0, o[nt], 0, 0, 0);
      o[nt] = __builtin_amdgcn_mfma_f32_16x16x32_bf16(pa1, v1, o[nt], 0, 0, 0);
    }
  }
  // ---- write per-wave partials ----
  #pragma unroll
  for (int nt = 0; nt < 4; ++nt)
    #pragma unroll
    for (int r = 0; r < 4; ++r)
      Om[w][lq * 4 + r][nt * 16 + l15] = o[nt][r];
  if (l15 == 0) {
    #pragma unroll
    for (int r = 0; r < 4; ++r) {
      Mm[w][lq * 4 + r] = mrow[r];
      Lm[w][lq * 4 + r] = lrow[r];
    }
  }
  __syncthreads();
  // ---- merge: wave w produces output col group [w*16, w*16+16) ----
  #pragma unroll
  for (int r = 0; r < 4; ++r) {
    int row = lq * 4 + r;
    float m0 = Mm[0][row], m1 = Mm[1][row], m2 = Mm[2][row], m3 = Mm[3][row];
    float M = fmaxf(fmaxf(m0, m1), fmaxf(m2, m3));
    float s0 = __expf(m0 - M), s1 = __expf(m1 - M);
    float s2 = __expf(m2 - M), s3 = __expf(m3 - M);
    float L = Lm[0][row] * s0 + Lm[1][row] * s1 + Lm[2][row] * s2 + Lm[3][row] * s3;
    int col = w * 16 + l15;
    float val = Om[0][row][col] * s0 + Om[1][row][col] * s1 +
                Om[2][row][col] * s2 + Om[3][row][col] * s3;
    out[((size_t)(b * TT + row0 + row)) * DH + col] = val / L;
  }
}

extern "C" void kernel_launch(void* const* d_in, const int* in_sizes, int n_in,
                              void* d_out, int out_size, void* d_ws, size_t ws_size,
                              hipStream_t stream) {
  const float* x  = (const float*)d_in[0];
  const float* Wq = (const float*)d_in[1];
  const float* Wk = (const float*)d_in[2];
  const float* Wv = (const float*)d_in[3];
  float* out = (float*)d_out;
  char* ws = (char*)d_ws;
  // workspace layout (bf16): Qb 2MB | Kb 2MB | Vt 2MB | Wt 0.4MB
  short* Qb = (short*)(ws);
  short* Kb = (short*)(ws + (2ull << 20));
  short* Vt = (short*)(ws + (4ull << 20));
  short* Wt = (short*)(ws + (6ull << 20));

  convw_kernel<<<dim3(768), dim3(256), 0, stream>>>(Wq, Wk, Wv, Wt);
  proj_kernel<<<dim3(1024), dim3(192), 0, stream>>>(x, Wt, Qb, Kb, Vt);
  flash_kernel<<<dim3(1024), dim3(256), 0, stream>>>(Qb, Kb, Vt, out);
}

// Round 6
// 192.693 us; speedup vs baseline: 1.1727x; 1.0002x over previous
//
#include <hip/hip_runtime.h>
#include <hip/hip_bf16.h>

#define DM 1024
#define DH 64
#define TT 2048

typedef __attribute__((ext_vector_type(8))) short bf16x8;
typedef __attribute__((ext_vector_type(4))) short s16x4;
typedef __attribute__((ext_vector_type(4))) float f32x4;

static __device__ __forceinline__ short f2bf(float f) {
  union { __hip_bfloat16 h; short s; } u;
  u.h = __float2bfloat16(f);
  return u.s;
}

// ---------------- kernel 1: W -> W^T bf16, layout [3][64 n][1024 k] ----------------
__global__ __launch_bounds__(256) void convw_kernel(const float* __restrict__ Wq,
                                                    const float* __restrict__ Wk,
                                                    const float* __restrict__ Wv,
                                                    short* __restrict__ Wt) {
  int idx = blockIdx.x * 256 + threadIdx.x;
  if (idx >= 3 * 64 * 1024) return;
  int wsel = idx >> 16;
  int rem  = idx & 65535;
  int n = rem >> 10;
  int k = rem & 1023;
  const float* W = (wsel == 0) ? Wq : (wsel == 1) ? Wk : Wv;
  Wt[idx] = f2bf(W[k * DH + n]);
}

// ---------------- kernel 2: projection, split-K x2 ----------------
// 6 waves/block: wave = (out 0..2) x (khalf 0..1), 16 rows x 64 cols each.
// 1024 blocks x 384 thr = 6144 waves (6/SIMD).
// Qb,Kb: [B*T][64] bf16 row-major. Vt: [B][64 dim][2048 t] bf16 (transposed).
__global__ __launch_bounds__(384) void proj_kernel(const float* __restrict__ x,
                                                   const short* __restrict__ Wt,
                                                   short* __restrict__ Qb,
                                                   short* __restrict__ Kb,
                                                   short* __restrict__ Vt) {
  __shared__ float Red[3][16][68];   // kh=1 partials; 68-pad -> 2-way bank alias (free)
  int wid  = threadIdx.x >> 6;
  int w    = wid >> 1;               // 0=Q 1=K 2=V
  int kh   = wid & 1;                // K-half
  int lane = threadIdx.x & 63;
  int l15 = lane & 15, lq = lane >> 4;
  int row0 = blockIdx.x * 16;
  f32x4 acc[4];
  #pragma unroll
  for (int t = 0; t < 4; ++t) acc[t] = (f32x4){0.f, 0.f, 0.f, 0.f};

  const float* xp = x + (size_t)(row0 + l15) * DM + 8 * lq;
  const short* wbase = Wt + w * (DH * DM);
  #pragma unroll 2
  for (int ks = kh * 16; ks < kh * 16 + 16; ++ks) {
    const float4* ap = reinterpret_cast<const float4*>(xp + ks * 32);
    float4 a0 = ap[0], a1 = ap[1];
    bf16x8 af;
    af[0] = f2bf(a0.x); af[1] = f2bf(a0.y); af[2] = f2bf(a0.z); af[3] = f2bf(a0.w);
    af[4] = f2bf(a1.x); af[5] = f2bf(a1.y); af[6] = f2bf(a1.z); af[7] = f2bf(a1.w);
    const short* wp = wbase + (size_t)l15 * DM + ks * 32 + 8 * lq;
    #pragma unroll
    for (int nt = 0; nt < 4; ++nt) {
      bf16x8 bfr = *reinterpret_cast<const bf16x8*>(wp + (size_t)nt * 16 * DM);
      acc[nt] = __builtin_amdgcn_mfma_f32_16x16x32_bf16(af, bfr, acc[nt], 0, 0, 0);
    }
  }

  // kh=1 waves park partials in LDS
  if (kh == 1) {
    #pragma unroll
    for (int nt = 0; nt < 4; ++nt)
      #pragma unroll
      for (int r = 0; r < 4; ++r)
        Red[w][lq * 4 + r][nt * 16 + l15] = acc[nt][r];
  }
  __syncthreads();
  if (kh == 1) return;

  // kh=0 waves: combine + epilogue. D layout: col=lane&15, row=(lane>>4)*4+r
  #pragma unroll
  for (int nt = 0; nt < 4; ++nt)
    #pragma unroll
    for (int r = 0; r < 4; ++r)
      acc[nt][r] += Red[w][lq * 4 + r][nt * 16 + l15];

  if (w < 2) {
    short* dst = (w == 0) ? Qb : Kb;
    #pragma unroll
    for (int nt = 0; nt < 4; ++nt)
      #pragma unroll
      for (int r = 0; r < 4; ++r) {
        int row = row0 + lq * 4 + r;
        dst[(size_t)row * DH + nt * 16 + l15] = f2bf(acc[nt][r]);
      }
  } else {
    int b = row0 >> 11;            // blocks never straddle batches
    int tloc = (row0 & 2047) + lq * 4;
    #pragma unroll
    for (int nt = 0; nt < 4; ++nt) {
      int dim = nt * 16 + l15;
      s16x4 pk;
      #pragma unroll
      for (int r = 0; r < 4; ++r) pk[r] = f2bf(acc[nt][r]);
      *reinterpret_cast<s16x4*>(Vt + ((size_t)b * DH + dim) * TT + tloc) = pk;
    }
  }
}

// ---------------- kernel 3: causal flash attention, 8-way key split ----------------
// 8 waves/block on one 16-row Q tile; wave w: kt = w, w+8, ... with private
// online-softmax state; LDS merge. 1024 blocks x 512 thr = 8192 waves (8/SIMD).
// Pl (in-loop P transpose) and Om (post-loop partials) share LDS via union.
__global__ __launch_bounds__(512) void flash_kernel(const short* __restrict__ Qb,
                                                    const short* __restrict__ Kb,
                                                    const short* __restrict__ Vt,
                                                    float* __restrict__ out) {
  __shared__ union ShBuf {
    short Pl[8][16][72];   // per-wave; rows 144B -> 16B-aligned
    float Om[8][16][64];   // per-wave partial O (valid after post-loop barrier)
  } sh;
  __shared__ float Mm[8][16];
  __shared__ float Lm[8][16];
  __shared__ float Sc[8][16];
  __shared__ float Linv[16];
  int w    = threadIdx.x >> 6;
  int lane = threadIdx.x & 63;
  int l15 = lane & 15, lq = lane >> 4;
  int qt = 127 - (blockIdx.x >> 3);   // descending work order for load balance
  int b  = blockIdx.x & 7;
  int row0 = qt * 16;

  const short* qp = Qb + ((size_t)(b * TT + row0 + l15)) * DH + 8 * lq;
  bf16x8 qf0 = *reinterpret_cast<const bf16x8*>(qp);
  bf16x8 qf1 = *reinterpret_cast<const bf16x8*>(qp + 32);

  float mrow[4] = {-1e30f, -1e30f, -1e30f, -1e30f};
  float lrow[4] = {0.f, 0.f, 0.f, 0.f};
  f32x4 o[4];
  #pragma unroll
  for (int nt = 0; nt < 4; ++nt) o[nt] = (f32x4){0.f, 0.f, 0.f, 0.f};

  int nkt = (qt >> 2) + 1;       // causal: key tiles 0..(row0+15)/64
  for (int kt = w; kt < nkt; kt += 8) {
    int k0 = kt * 64;
    // ---- S = Q K^T ----
    f32x4 s[4];
    #pragma unroll
    for (int nt = 0; nt < 4; ++nt) s[nt] = (f32x4){0.f, 0.f, 0.f, 0.f};
    #pragma unroll
    for (int nt = 0; nt < 4; ++nt) {
      const short* kp = Kb + ((size_t)(b * TT + k0 + nt * 16 + l15)) * DH + 8 * lq;
      bf16x8 b0 = *reinterpret_cast<const bf16x8*>(kp);
      bf16x8 b1 = *reinterpret_cast<const bf16x8*>(kp + 32);
      s[nt] = __builtin_amdgcn_mfma_f32_16x16x32_bf16(qf0, b0, s[nt], 0, 0, 0);
      s[nt] = __builtin_amdgcn_mfma_f32_16x16x32_bf16(qf1, b1, s[nt], 0, 0, 0);
    }
    // ---- scale + causal mask + row max ----
    float rmax[4] = {-1e30f, -1e30f, -1e30f, -1e30f};
    #pragma unroll
    for (int nt = 0; nt < 4; ++nt) {
      int key = k0 + nt * 16 + l15;
      #pragma unroll
      for (int r = 0; r < 4; ++r) {
        int qr = row0 + lq * 4 + r;
        float v = s[nt][r] * 0.03125f;   // 1/sqrt(1024)
        v = (key <= qr) ? v : -1e30f;
        s[nt][r] = v;
        rmax[r] = fmaxf(rmax[r], v);
      }
    }
    #pragma unroll
    for (int r = 0; r < 4; ++r)
      #pragma unroll
      for (int d = 1; d < 16; d <<= 1)
        rmax[r] = fmaxf(rmax[r], __shfl_xor(rmax[r], d));
    // ---- online softmax update (per-wave private state) ----
    float alpha[4], rs[4];
    #pragma unroll
    for (int r = 0; r < 4; ++r) {
      float mn = fmaxf(mrow[r], rmax[r]);
      alpha[r] = __expf(mrow[r] - mn);
      mrow[r] = mn;
      rs[r] = 0.f;
    }
    #pragma unroll
    for (int nt = 0; nt < 4; ++nt)
      #pragma unroll
      for (int r = 0; r < 4; ++r) {
        float p = __expf(s[nt][r] - mrow[r]);
        s[nt][r] = p;
        rs[r] += p;
      }
    #pragma unroll
    for (int r = 0; r < 4; ++r) {
      #pragma unroll
      for (int d = 1; d < 16; d <<= 1)
        rs[r] += __shfl_xor(rs[r], d);
      lrow[r] = lrow[r] * alpha[r] + rs[r];
    }
    #pragma unroll
    for (int nt = 0; nt < 4; ++nt) {
      o[nt][0] *= alpha[0]; o[nt][1] *= alpha[1];
      o[nt][2] *= alpha[2]; o[nt][3] *= alpha[3];
    }
    // ---- P (D-layout) -> LDS transpose -> A-operand layout (wave-private) ----
    #pragma unroll
    for (int nt = 0; nt < 4; ++nt)
      #pragma unroll
      for (int r = 0; r < 4; ++r)
        sh.Pl[w][lq * 4 + r][nt * 16 + l15] = f2bf(s[nt][r]);
    // same-wave DS ops in-order; buffer is wave-private -> no barrier
    bf16x8 pa0 = *reinterpret_cast<const bf16x8*>(&sh.Pl[w][l15][8 * lq]);
    bf16x8 pa1 = *reinterpret_cast<const bf16x8*>(&sh.Pl[w][l15][32 + 8 * lq]);
    // ---- O += P V ----
    #pragma unroll
    for (int nt = 0; nt < 4; ++nt) {
      const short* vp = Vt + ((size_t)(b * DH + nt * 16 + l15)) * TT + k0 + 8 * lq;
      bf16x8 v0 = *reinterpret_cast<const bf16x8*>(vp);
      bf16x8 v1 = *reinterpret_cast<const bf16x8*>(vp + 32);
      o[nt] = __builtin_amdgcn_mfma_f32_16x16x32_bf16(pa0, v0, o[nt], 0, 0, 0);
      o[nt] = __builtin_amdgcn_mfma_f32_16x16x32_bf16(pa1, v1, o[nt], 0, 0, 0);
    }
  }
  // ---- all waves done with Pl before Om overwrites it ----
  __syncthreads();
  #pragma unroll
  for (int nt = 0; nt < 4; ++nt)
    #pragma unroll
    for (int r = 0; r < 4; ++r)
      sh.Om[w][lq * 4 + r][nt * 16 + l15] = o[nt][r];
  if (l15 == 0) {
    #pragma unroll
    for (int r = 0; r < 4; ++r) {
      Mm[w][lq * 4 + r] = mrow[r];
      Lm[w][lq * 4 + r] = lrow[r];
    }
  }
  __syncthreads();
  // ---- per-row combine factors (threads 0..15) ----
  if (threadIdx.x < 16) {
    int row = threadIdx.x;
    float M = -1e30f;
    #pragma unroll
    for (int v = 0; v < 8; ++v) M = fmaxf(M, Mm[v][row]);
    float L = 0.f;
    #pragma unroll
    for (int v = 0; v < 8; ++v) {
      float sv = __expf(Mm[v][row] - M);
      Sc[v][row] = sv;
      L += Lm[v][row] * sv;
    }
    Linv[row] = 1.0f / L;
  }
  __syncthreads();
  // ---- merge: 1024 outputs over 512 threads, coalesced ----
  int e = threadIdx.x;
  #pragma unroll
  for (int i = 0; i < 2; ++i, e += 512) {
    int row = e >> 6, col = e & 63;
    float val = 0.f;
    #pragma unroll
    for (int v = 0; v < 8; ++v) val += sh.Om[v][row][col] * Sc[v][row];
    out[((size_t)(b * TT + row0 + row)) * DH + col] = val * Linv[row];
  }
}

extern "C" void kernel_launch(void* const* d_in, const int* in_sizes, int n_in,
                              void* d_out, int out_size, void* d_ws, size_t ws_size,
                              hipStream_t stream) {
  const float* x  = (const float*)d_in[0];
  const float* Wq = (const float*)d_in[1];
  const float* Wk = (const float*)d_in[2];
  const float* Wv = (const float*)d_in[3];
  float* out = (float*)d_out;
  char* ws = (char*)d_ws;
  // workspace layout (bf16): Qb 2MB | Kb 2MB | Vt 2MB | Wt 0.4MB
  short* Qb = (short*)(ws);
  short* Kb = (short*)(ws + (2ull << 20));
  short* Vt = (short*)(ws + (4ull << 20));
  short* Wt = (short*)(ws + (6ull << 20));

  convw_kernel<<<dim3(768), dim3(256), 0, stream>>>(Wq, Wk, Wv, Wt);
  proj_kernel<<<dim3(1024), dim3(384), 0, stream>>>(x, Wt, Qb, Kb, Vt);
  flash_kernel<<<dim3(1024), dim3(512), 0, stream>>>(Qb, Kb, Vt, out);
}

// Round 7
// 153.910 us; speedup vs baseline: 1.4682x; 1.2520x over previous
//
#include <hip/hip_runtime.h>
#include <hip/hip_bf16.h>

#define DM 1024
#define DH 64
#define TT 2048

typedef __attribute__((ext_vector_type(8))) short bf16x8;
typedef __attribute__((ext_vector_type(4))) short s16x4;
typedef __attribute__((ext_vector_type(4))) float f32x4;

static __device__ __forceinline__ short f2bf(float f) {
  union { __hip_bfloat16 h; short s; } u;
  u.h = __float2bfloat16(f);
  return u.s;
}

// ---------------- kernel 1: W -> W^T bf16, layout [3][64 n][1024 k] ----------------
__global__ __launch_bounds__(256) void convw_kernel(const float* __restrict__ Wq,
                                                    const float* __restrict__ Wk,
                                                    const float* __restrict__ Wv,
                                                    short* __restrict__ Wt) {
  int idx = blockIdx.x * 256 + threadIdx.x;
  if (idx >= 3 * 64 * 1024) return;
  int wsel = idx >> 16;
  int rem  = idx & 65535;
  int n = rem >> 10;
  int k = rem & 1023;
  const float* W = (wsel == 0) ? Wq : (wsel == 1) ? Wk : Wv;
  Wt[idx] = f2bf(W[k * DH + n]);
}

// ---------------- kernel 2: projection as tiled GEMM ----------------
// M=16384, N=192 (q|k|v), K=1024. Block = 64 rows x 192 cols, 256 blocks.
// 8 waves (4M x 2N): wave = 16 rows x 96 cols = 1x6 frags of 16x16.
// BK=64 steps; x converted f32->bf16 during reg-staged LDS store; x read ONCE.
// LDS rows are 128B -> T2 XOR swizzle on write AND read (16-way conflict otherwise).
__global__ __launch_bounds__(512, 4) void proj_kernel(const float* __restrict__ x,
                                                      const short* __restrict__ Wt,
                                                      short* __restrict__ Qb,
                                                      short* __restrict__ Kb,
                                                      short* __restrict__ Vt) {
  __shared__ short As[64 * 64];    // [row 64][k 64] bf16, swizzled, 8 KB
  __shared__ short Bs[192 * 64];   // [n 192][k 64] bf16, swizzled, 24 KB
  char* Ab = (char*)As;
  char* Bb = (char*)Bs;
  int tid  = threadIdx.x;
  int lane = tid & 63;
  int wid  = tid >> 6;
  int l15 = lane & 15, lq = lane >> 4;
  int wr = wid >> 1, wc = wid & 1;          // 4M x 2N wave grid
  int row0 = blockIdx.x * 64;

  // --- staging assignments ---
  // A: thread -> (row = tid>>3, 32B chunk cg = tid&7); reads 32B fp32, writes 16B bf16
  int arow = tid >> 3, acg = tid & 7;
  const float* axp = x + (size_t)(row0 + arow) * DM + acg * 8;
  int abyte = arow * 128 + ((acg * 16) ^ ((arow & 7) << 4));
  // B: threads 0..383 -> (n = tid>>1, half h = tid&1); reads 64B bf16 contiguous
  int brow = tid >> 1, bh = tid & 1;
  const short* bwp = Wt + (size_t)brow * DM + bh * 32;
  int bswz = (brow & 7) << 4;
  int bbyte[4];
  #pragma unroll
  for (int i = 0; i < 4; ++i) bbyte[i] = brow * 128 + ((bh * 64 + i * 16) ^ bswz);

  // --- prologue: load step 0 into regs ---
  float4 pa0 = ((const float4*)axp)[0];
  float4 pa1 = ((const float4*)axp)[1];
  bf16x8 pb[4];
  if (tid < 384) {
    #pragma unroll
    for (int i = 0; i < 4; ++i) pb[i] = ((const bf16x8*)bwp)[i];
  }

  f32x4 acc[6];
  #pragma unroll
  for (int n = 0; n < 6; ++n) acc[n] = (f32x4){0.f, 0.f, 0.f, 0.f};

  for (int s = 0; s < 16; ++s) {
    // --- commit staged regs to LDS (convert A to bf16) ---
    bf16x8 aw;
    aw[0] = f2bf(pa0.x); aw[1] = f2bf(pa0.y); aw[2] = f2bf(pa0.z); aw[3] = f2bf(pa0.w);
    aw[4] = f2bf(pa1.x); aw[5] = f2bf(pa1.y); aw[6] = f2bf(pa1.z); aw[7] = f2bf(pa1.w);
    *(bf16x8*)(Ab + abyte) = aw;
    if (tid < 384) {
      #pragma unroll
      for (int i = 0; i < 4; ++i) *(bf16x8*)(Bb + bbyte[i]) = pb[i];
    }
    __syncthreads();
    // --- prefetch next step's globals (latency hides under compute) ---
    if (s < 15) {
      const float* nax = axp + (s + 1) * 64;
      pa0 = ((const float4*)nax)[0];
      pa1 = ((const float4*)nax)[1];
      if (tid < 384) {
        const short* nbw = bwp + (s + 1) * 64;
        #pragma unroll
        for (int i = 0; i < 4; ++i) pb[i] = ((const bf16x8*)nbw)[i];
      }
    }
    // --- compute: 12 MFMA on staged tiles ---
    #pragma unroll
    for (int kk = 0; kk < 2; ++kk) {
      int koff = (kk * 64 + lq * 16) ^ ((l15 & 7) << 4);
      bf16x8 af = *(const bf16x8*)(Ab + (wr * 16 + l15) * 128 + koff);
      bf16x8 bf[6];
      #pragma unroll
      for (int nc = 0; nc < 6; ++nc)
        bf[nc] = *(const bf16x8*)(Bb + (wc * 96 + nc * 16 + l15) * 128 + koff);
      #pragma unroll
      for (int nc = 0; nc < 6; ++nc)
        acc[nc] = __builtin_amdgcn_mfma_f32_16x16x32_bf16(af, bf[nc], acc[nc], 0, 0, 0);
    }
    __syncthreads();
  }

  // --- epilogue: D layout col=l15, row=lq*4+r ---
  int growb = row0 + wr * 16 + lq * 4;
  #pragma unroll
  for (int nc = 0; nc < 6; ++nc) {
    int gcolb = wc * 96 + nc * 16;
    int mat = gcolb >> 6;
    int mc  = (gcolb & 63) + l15;
    if (mat == 0) {
      #pragma unroll
      for (int r = 0; r < 4; ++r)
        Qb[(size_t)(growb + r) * DH + mc] = f2bf(acc[nc][r]);
    } else if (mat == 1) {
      #pragma unroll
      for (int r = 0; r < 4; ++r)
        Kb[(size_t)(growb + r) * DH + mc] = f2bf(acc[nc][r]);
    } else {
      int b = growb >> 11;           // 64-row blocks never straddle batches
      int tl = growb & 2047;
      s16x4 pk;
      #pragma unroll
      for (int r = 0; r < 4; ++r) pk[r] = f2bf(acc[nc][r]);
      *(s16x4*)(Vt + ((size_t)(b * DH + mc)) * TT + tl) = pk;
    }
  }
}

// ---------------- kernel 3: causal flash attention, 8-way key split ----------------
// (unchanged from round 6 — single-variable A/B on proj this round)
__global__ __launch_bounds__(512) void flash_kernel(const short* __restrict__ Qb,
                                                    const short* __restrict__ Kb,
                                                    const short* __restrict__ Vt,
                                                    float* __restrict__ out) {
  __shared__ union ShBuf {
    short Pl[8][16][72];
    float Om[8][16][64];
  } sh;
  __shared__ float Mm[8][16];
  __shared__ float Lm[8][16];
  __shared__ float Sc[8][16];
  __shared__ float Linv[16];
  int w    = threadIdx.x >> 6;
  int lane = threadIdx.x & 63;
  int l15 = lane & 15, lq = lane >> 4;
  int qt = 127 - (blockIdx.x >> 3);
  int b  = blockIdx.x & 7;
  int row0 = qt * 16;

  const short* qp = Qb + ((size_t)(b * TT + row0 + l15)) * DH + 8 * lq;
  bf16x8 qf0 = *reinterpret_cast<const bf16x8*>(qp);
  bf16x8 qf1 = *reinterpret_cast<const bf16x8*>(qp + 32);

  float mrow[4] = {-1e30f, -1e30f, -1e30f, -1e30f};
  float lrow[4] = {0.f, 0.f, 0.f, 0.f};
  f32x4 o[4];
  #pragma unroll
  for (int nt = 0; nt < 4; ++nt) o[nt] = (f32x4){0.f, 0.f, 0.f, 0.f};

  int nkt = (qt >> 2) + 1;
  for (int kt = w; kt < nkt; kt += 8) {
    int k0 = kt * 64;
    f32x4 s[4];
    #pragma unroll
    for (int nt = 0; nt < 4; ++nt) s[nt] = (f32x4){0.f, 0.f, 0.f, 0.f};
    #pragma unroll
    for (int nt = 0; nt < 4; ++nt) {
      const short* kp = Kb + ((size_t)(b * TT + k0 + nt * 16 + l15)) * DH + 8 * lq;
      bf16x8 b0 = *reinterpret_cast<const bf16x8*>(kp);
      bf16x8 b1 = *reinterpret_cast<const bf16x8*>(kp + 32);
      s[nt] = __builtin_amdgcn_mfma_f32_16x16x32_bf16(qf0, b0, s[nt], 0, 0, 0);
      s[nt] = __builtin_amdgcn_mfma_f32_16x16x32_bf16(qf1, b1, s[nt], 0, 0, 0);
    }
    float rmax[4] = {-1e30f, -1e30f, -1e30f, -1e30f};
    #pragma unroll
    for (int nt = 0; nt < 4; ++nt) {
      int key = k0 + nt * 16 + l15;
      #pragma unroll
      for (int r = 0; r < 4; ++r) {
        int qr = row0 + lq * 4 + r;
        float v = s[nt][r] * 0.03125f;
        v = (key <= qr) ? v : -1e30f;
        s[nt][r] = v;
        rmax[r] = fmaxf(rmax[r], v);
      }
    }
    #pragma unroll
    for (int r = 0; r < 4; ++r)
      #pragma unroll
      for (int d = 1; d < 16; d <<= 1)
        rmax[r] = fmaxf(rmax[r], __shfl_xor(rmax[r], d));
    float alpha[4], rs[4];
    #pragma unroll
    for (int r = 0; r < 4; ++r) {
      float mn = fmaxf(mrow[r], rmax[r]);
      alpha[r] = __expf(mrow[r] - mn);
      mrow[r] = mn;
      rs[r] = 0.f;
    }
    #pragma unroll
    for (int nt = 0; nt < 4; ++nt)
      #pragma unroll
      for (int r = 0; r < 4; ++r) {
        float p = __expf(s[nt][r] - mrow[r]);
        s[nt][r] = p;
        rs[r] += p;
      }
    #pragma unroll
    for (int r = 0; r < 4; ++r) {
      #pragma unroll
      for (int d = 1; d < 16; d <<= 1)
        rs[r] += __shfl_xor(rs[r], d);
      lrow[r] = lrow[r] * alpha[r] + rs[r];
    }
    #pragma unroll
    for (int nt = 0; nt < 4; ++nt) {
      o[nt][0] *= alpha[0]; o[nt][1] *= alpha[1];
      o[nt][2] *= alpha[2]; o[nt][3] *= alpha[3];
    }
    #pragma unroll
    for (int nt = 0; nt < 4; ++nt)
      #pragma unroll
      for (int r = 0; r < 4; ++r)
        sh.Pl[w][lq * 4 + r][nt * 16 + l15] = f2bf(s[nt][r]);
    bf16x8 pa0 = *reinterpret_cast<const bf16x8*>(&sh.Pl[w][l15][8 * lq]);
    bf16x8 pa1 = *reinterpret_cast<const bf16x8*>(&sh.Pl[w][l15][32 + 8 * lq]);
    #pragma unroll
    for (int nt = 0; nt < 4; ++nt) {
      const short* vp = Vt + ((size_t)(b * DH + nt * 16 + l15)) * TT + k0 + 8 * lq;
      bf16x8 v0 = *reinterpret_cast<const bf16x8*>(vp);
      bf16x8 v1 = *reinterpret_cast<const bf16x8*>(vp + 32);
      o[nt] = __builtin_amdgcn_mfma_f32_16x16x32_bf16(pa0, v0, o[nt], 0, 0, 0);
      o[nt] = __builtin_amdgcn_mfma_f32_16x16x32_bf16(pa1, v1, o[nt], 0, 0, 0);
    }
  }
  __syncthreads();
  #pragma unroll
  for (int nt = 0; nt < 4; ++nt)
    #pragma unroll
    for (int r = 0; r < 4; ++r)
      sh.Om[w][lq * 4 + r][nt * 16 + l15] = o[nt][r];
  if (l15 == 0) {
    #pragma unroll
    for (int r = 0; r < 4; ++r) {
      Mm[w][lq * 4 + r] = mrow[r];
      Lm[w][lq * 4 + r] = lrow[r];
    }
  }
  __syncthreads();
  if (threadIdx.x < 16) {
    int row = threadIdx.x;
    float M = -1e30f;
    #pragma unroll
    for (int v = 0; v < 8; ++v) M = fmaxf(M, Mm[v][row]);
    float L = 0.f;
    #pragma unroll
    for (int v = 0; v < 8; ++v) {
      float sv = __expf(Mm[v][row] - M);
      Sc[v][row] = sv;
      L += Lm[v][row] * sv;
    }
    Linv[row] = 1.0f / L;
  }
  __syncthreads();
  int e = threadIdx.x;
  #pragma unroll
  for (int i = 0; i < 2; ++i, e += 512) {
    int row = e >> 6, col = e & 63;
    float val = 0.f;
    #pragma unroll
    for (int v = 0; v < 8; ++v) val += sh.Om[v][row][col] * Sc[v][row];
    out[((size_t)(b * TT + row0 + row)) * DH + col] = val * Linv[row];
  }
}

extern "C" void kernel_launch(void* const* d_in, const int* in_sizes, int n_in,
                              void* d_out, int out_size, void* d_ws, size_t ws_size,
                              hipStream_t stream) {
  const float* x  = (const float*)d_in[0];
  const float* Wq = (const float*)d_in[1];
  const float* Wk = (const float*)d_in[2];
  const float* Wv = (const float*)d_in[3];
  float* out = (float*)d_out;
  char* ws = (char*)d_ws;
  // workspace layout (bf16): Qb 2MB | Kb 2MB | Vt 2MB | Wt 0.4MB
  short* Qb = (short*)(ws);
  short* Kb = (short*)(ws + (2ull << 20));
  short* Vt = (short*)(ws + (4ull << 20));
  short* Wt = (short*)(ws + (6ull << 20));

  convw_kernel<<<dim3(768), dim3(256), 0, stream>>>(Wq, Wk, Wv, Wt);
  proj_kernel<<<dim3(256), dim3(512), 0, stream>>>(x, Wt, Qb, Kb, Vt);
  flash_kernel<<<dim3(1024), dim3(512), 0, stream>>>(Qb, Kb, Vt, out);
}